// Round 23
// baseline (59.859 us; speedup 1.0000x reference)
//
#include <hip/hip_runtime.h>
#include <hip/hip_bf16.h>
#include <stdint.h>

typedef __attribute__((ext_vector_type(4)))  int i32x4;
typedef __attribute__((ext_vector_type(16))) int i32x16;

#define N_ROWS  32768   // 64 * 512
#define N_CODES 1024
#define DIM     512

typedef const __attribute__((address_space(1))) uint32_t guint;
typedef __attribute__((address_space(3))) uint32_t luint;
static __device__ __forceinline__ void gl_lds16(const char* g, char* l) {
    __builtin_amdgcn_global_load_lds((guint*)g, (luint*)l, 16, 0, 0);
}

static __device__ __forceinline__ int q8(float v) {
    int q = __float2int_rn(v * 32.0f);
    return max(-127, min(127, q));
}
static __device__ __forceinline__ uint32_t pack4(float a, float b, float c, float d) {
    return (uint32_t)(q8(a) & 0xFF) | ((uint32_t)(q8(b) & 0xFF) << 8)
         | ((uint32_t)(q8(c) & 0xFF) << 16) | ((uint32_t)(q8(d) & 0xFF) << 24);
}

// ---------------- K0: quantize W to i8 (scale 32) + exact f32 norms ----------------
__global__ void __launch_bounds__(256)
convertW(const float* __restrict__ W, char* __restrict__ Wq,
         float* __restrict__ wnorm) {
    const int lane = threadIdx.x & 63;
    const int code = blockIdx.x * 4 + (threadIdx.x >> 6);
    const float4* p = (const float4*)(W + (size_t)code * DIM + lane * 8);
    float4 a = p[0], b = p[1];
    *(uint2*)(Wq + (size_t)code * DIM + lane * 8) =
        make_uint2(pack4(a.x, a.y, a.z, a.w), pack4(b.x, b.y, b.z, b.w));
    float s = a.x*a.x + a.y*a.y + a.z*a.z + a.w*a.w
            + b.x*b.x + b.y*b.y + b.z*b.z + b.w*b.w;
    #pragma unroll
    for (int d = 1; d < 64; d <<= 1) s += __shfl_xor(s, d);
    if (lane == 0) wnorm[code] = s;
}

// ---------------- K1: fused X-quantize + A-resident 32x32x32-i8 barrier-free GEMM ----------------
// R22 structure (47.4us champion) with the MFMA shape switched to
// mfma_i32_32x32x32_i8: same 2KB of fragments per instruction but 2x the
// MACs -> loop LDS traffic per MAC drops 33% (the measured binding pipe,
// 93% of loop wall). Wave tile 64x128 = 2x2 tiles of 32x32 per 64-col
// ct-pair, K-step 32 (16 steps/ctp, 64 total). Per step: 2 A-reads +
// 2 B-reads + 2 wave-private gl_lds, counted vmcnt(2), zero barriers.
// Bank-exact swizzles (<=2-way = free): A 64B-rows, phys slot
// ((kt&1)*2+kh) ^ ((r>>1)&3); B 32B-rows, phys kh ^ ((r>>2)&1), staged
// with pre-swizzled source (l&1)^((l>>3)&1). C/D: col=lane&31,
// row=(reg&3)+8*(reg>>2)+4*(lane>>5) (verified, dtype-independent).
// XCD row-chunk (bid = xcd + 8*rl). LDS 57.6KB -> 2 blocks/CU.
__global__ void __launch_bounds__(256, 2)
gemm_argmin(const float* __restrict__ X, const char* __restrict__ Wq,
            const float* __restrict__ wnorm, float* __restrict__ partial) {
    __shared__ __align__(16) char As[8 * 4096];        // 32 KB: [kt64][row][slot]
    __shared__ __align__(16) char Bs[4 * 3 * 2048];    // 24 KB: [wave][buf][2KB]
    __shared__ float xnS[64];

    const int tid  = threadIdx.x;
    const int lane = tid & 63;
    const int wave = tid >> 6;
    const int l31 = lane & 31, kh = lane >> 5;
    const int arsw = (l31 >> 1) & 3;              // A read-slot XOR
    const int brsw = (l31 >> 2) & 1;              // B read-slot XOR

    // XCD row-chunk swizzle: bid = xcd + 8*rl; grid 512.
    const int bid = blockIdx.x;
    const int rowBase = ((bid & 7) * 64 + (bid >> 3)) * 64;
    const int colW = wave * 256;                  // wave's private col swath

    // B staging: buffer row r (=col) staged by lanes 2(r&31)+b via instr
    // j=r>>5; phys slot b holds logical sl = b ^ ((r>>2)&1) -> source slot
    // pre-swizzle (l&1)^((l>>3)&1). Linear gl_lds dest.
    const char* bS = Wq + (size_t)(colW + (lane >> 1)) * DIM
                   + (((lane & 1) ^ ((lane >> 3) & 1)) * 16);
    char* bD = Bs + wave * 6144 + lane * 16;

#define STAGE_B(s) do {                                                       \
    const int ctp_ = (s) >> 4, kt_ = (s) & 15, buf_ = (s) % 3;                \
    _Pragma("unroll")                                                         \
    for (int j = 0; j < 2; ++j)                                               \
        gl_lds16(bS + (size_t)(ctp_ * 64 + j * 32) * DIM + kt_ * 32,          \
                 bD + buf_ * 2048 + j * 1024);                                \
  } while (0)

    // ---- issue B(0), B(1) first: they land under the long f32 prologue ----
    STAGE_B(0);
    STAGE_B(1);

    // ---- prologue: f32 X strip -> exact xnorm + i8 into resident As ----
    const int r = tid >> 2, q4 = tid & 3;
    const int rsw = (r >> 1) & 3;                 // row's A slot XOR
    float nrm = 0.f;
    {
        const float* xP = X + (size_t)(rowBase + r) * DIM + q4 * 128;
        #pragma unroll
        for (int c = 0; c < 8; ++c) {             // 8 chunks of 16 elements
            float4 f0 = *(const float4*)(xP + c * 16);
            float4 f1 = *(const float4*)(xP + c * 16 + 4);
            float4 f2 = *(const float4*)(xP + c * 16 + 8);
            float4 f3 = *(const float4*)(xP + c * 16 + 12);
            nrm += f0.x*f0.x + f0.y*f0.y + f0.z*f0.z + f0.w*f0.w
                 + f1.x*f1.x + f1.y*f1.y + f1.z*f1.z + f1.w*f1.w
                 + f2.x*f2.x + f2.y*f2.y + f2.z*f2.z + f2.w*f2.w
                 + f3.x*f3.x + f3.y*f3.y + f3.z*f3.z + f3.w*f3.w;
            i32x4 v = { (int)pack4(f0.x, f0.y, f0.z, f0.w),
                        (int)pack4(f1.x, f1.y, f1.z, f1.w),
                        (int)pack4(f2.x, f2.y, f2.z, f2.w),
                        (int)pack4(f3.x, f3.y, f3.z, f3.w) };
            const int kt = 2 * q4 + (c >> 2), sl = c & 3;
            *(i32x4*)&As[kt * 4096 + r * 64 + (sl ^ rsw) * 16] = v;
        }
        nrm += __shfl_xor(nrm, 1);
        nrm += __shfl_xor(nrm, 2);
        if ((tid & 3) == 0) xnS[r] = nrm;
    }
    // preload wnorm into regs (keeps in-loop vmcnt clean)
    float wnR[4][2];
    #pragma unroll
    for (int c = 0; c < 4; ++c)
        #pragma unroll
        for (int n = 0; n < 2; ++n)
            wnR[c][n] = wnorm[colW + c * 64 + n * 32 + l31];
    __syncthreads();   // As visible to all; drains B(0),B(1) + X loads

    i32x16 acc[2][2];
    #pragma unroll
    for (int m = 0; m < 2; ++m)
        #pragma unroll
        for (int n = 0; n < 2; ++n) acc[m][n] = (i32x16)0;
    uint32_t runKey[2][16];
    #pragma unroll
    for (int m = 0; m < 2; ++m)
        #pragma unroll
        for (int g = 0; g < 16; ++g) runKey[m][g] = 0xFFFFFFFFu;

    const char* bR = Bs + wave * 6144;

    for (int ctp = 0; ctp < 4; ++ctp) {
        #pragma unroll
        for (int kt = 0; kt < 16; ++kt) {
            const int s = ctp * 16 + kt;
            const int buf = s % 3;
            i32x4 aF[2], bF[2];
            #pragma unroll
            for (int m = 0; m < 2; ++m)
                aF[m] = *(const i32x4*)&As[(kt >> 1) * 4096
                        + (m * 32 + l31) * 64
                        + ((((kt & 1) * 2 + kh) ^ arsw) * 16)];
            #pragma unroll
            for (int n = 0; n < 2; ++n)
                bF[n] = *(const i32x4*)&bR[buf * 2048
                        + (n * 32 + l31) * 32 + ((kh ^ brsw) * 16)];
            if (s + 2 < 64) STAGE_B(s + 2);       // depth-2, wave-private
            #pragma unroll
            for (int m = 0; m < 2; ++m)
                #pragma unroll
                for (int n = 0; n < 2; ++n)
                    acc[m][n] = __builtin_amdgcn_mfma_i32_32x32x32_i8(
                        aF[m], bF[n], acc[m][n], 0, 0, 0);
            if (s + 2 < 64)   asm volatile("s_waitcnt vmcnt(2)" ::: "memory");
            else if (s == 62) asm volatile("s_waitcnt vmcnt(0)" ::: "memory");
        }
        // ct-pair complete: fold scores into running packed keys
        #pragma unroll
        for (int n = 0; n < 2; ++n) {
            const int wcol = colW + ctp * 64 + n * 32 + l31;
            const float wn = wnR[ctp][n];
            #pragma unroll
            for (int m = 0; m < 2; ++m)
                #pragma unroll
                for (int g = 0; g < 16; ++g) {
                    float sc = wn - (float)acc[m][n][g] * 0.001953125f;
                    uint32_t u = __float_as_uint(sc);
                    u = (u & 0x80000000u) ? ~u : (u | 0x80000000u);
                    runKey[m][g] = min(runKey[m][g],
                                       (u & ~1023u) | (uint32_t)wcol);
                }
        }
        #pragma unroll
        for (int m = 0; m < 2; ++m)
            #pragma unroll
            for (int n = 0; n < 2; ++n) acc[m][n] = (i32x16)0;
    }
#undef STAGE_B

    // ---- per-wave 32-lane col reduce; lanes 0 & 32 write distinct rows ----
    uint32_t* kbuf = (uint32_t*)(Bs + wave * 6144);   // own region, loop done
    #pragma unroll
    for (int m = 0; m < 2; ++m)
        #pragma unroll
        for (int g = 0; g < 16; ++g) {
            uint32_t k = runKey[m][g];
            #pragma unroll
            for (int d = 1; d < 32; d <<= 1)
                k = min(k, (uint32_t)__shfl_xor((int)k, d));
            if (l31 == 0)
                kbuf[m * 32 + (g & 3) + 8 * (g >> 2) + 4 * kh] = k;
        }
    __syncthreads();

    // ---- wave 0: merge 4 waves' keys per row, add exact xnorm, block sum ----
    if (wave == 0) {
        const uint32_t* k0 = (const uint32_t*)(Bs);
        uint32_t k = min(min(k0[lane], k0[1536 + lane]),
                         min(k0[3072 + lane], k0[4608 + lane]));
        uint32_t sb = k & ~1023u;
        float sc = (sb & 0x80000000u) ? __uint_as_float(sb ^ 0x80000000u)
                                      : __uint_as_float(~sb);
        float v = xnS[lane] + sc;
        #pragma unroll
        for (int d = 1; d < 64; d <<= 1) v += __shfl_xor(v, d);
        if (lane == 0) partial[bid] = v;
    }
}

// ---------------- K2: final mean over 512 partials (double accum) ----------------
__global__ void __launch_bounds__(256)
finalize(const float* __restrict__ partial, float* __restrict__ out) {
    __shared__ double sm[256];
    sm[threadIdx.x] = (double)partial[threadIdx.x]
                    + (double)partial[threadIdx.x + 256];
    __syncthreads();
    for (int st = 128; st > 0; st >>= 1) {
        if (threadIdx.x < st) sm[threadIdx.x] += sm[threadIdx.x + st];
        __syncthreads();
    }
    if (threadIdx.x == 0)
        out[0] = (float)(sm[0] / (double)((size_t)N_ROWS * DIM));
}

extern "C" void kernel_launch(void* const* d_in, const int* in_sizes, int n_in,
                              void* d_out, int out_size, void* d_ws, size_t ws_size,
                              hipStream_t stream) {
    const float* X = (const float*)d_in[0];   // [32768][512]
    const float* W = (const float*)d_in[1];   // [1024][512]
    char* ws = (char*)d_ws;
    char*   Wq      = ws;                            // 512 KB @ 0
    float*  wnorm   = (float*)(ws + 524288);         // 4 KB
    float*  partial = (float*)(ws + 528384);         // 2 KB
    float*  out     = (float*)d_out;

    convertW<<<N_CODES / 4, 256, 0, stream>>>(W, Wq, wnorm);
    gemm_argmin<<<512, 256, 0, stream>>>(X, Wq, wnorm, partial);
    finalize<<<1, 256, 0, stream>>>(partial, out);
}

// Round 24
// 47.537 us; speedup vs baseline: 1.2592x; 1.2592x over previous
//
#include <hip/hip_runtime.h>
#include <hip/hip_bf16.h>
#include <stdint.h>

typedef __attribute__((ext_vector_type(4))) int i32x4;

#define N_ROWS  32768   // 64 * 512
#define N_CODES 1024
#define DIM     512

typedef const __attribute__((address_space(1))) uint32_t guint;
typedef __attribute__((address_space(3))) uint32_t luint;
static __device__ __forceinline__ void gl_lds16(const char* g, char* l) {
    __builtin_amdgcn_global_load_lds((guint*)g, (luint*)l, 16, 0, 0);
}

static __device__ __forceinline__ int q8(float v) {
    int q = __float2int_rn(v * 32.0f);
    return max(-127, min(127, q));
}
static __device__ __forceinline__ uint32_t pack4(float a, float b, float c, float d) {
    return (uint32_t)(q8(a) & 0xFF) | ((uint32_t)(q8(b) & 0xFF) << 8)
         | ((uint32_t)(q8(c) & 0xFF) << 16) | ((uint32_t)(q8(d) & 0xFF) << 24);
}

// ---------------- K0: quantize W to i8 (scale 32) + exact f32 norms ----------------
__global__ void __launch_bounds__(256)
convertW(const float* __restrict__ W, char* __restrict__ Wq,
         float* __restrict__ wnorm) {
    const int lane = threadIdx.x & 63;
    const int code = blockIdx.x * 4 + (threadIdx.x >> 6);
    const float4* p = (const float4*)(W + (size_t)code * DIM + lane * 8);
    float4 a = p[0], b = p[1];
    *(uint2*)(Wq + (size_t)code * DIM + lane * 8) =
        make_uint2(pack4(a.x, a.y, a.z, a.w), pack4(b.x, b.y, b.z, b.w));
    float s = a.x*a.x + a.y*a.y + a.z*a.z + a.w*a.w
            + b.x*b.x + b.y*b.y + b.z*b.z + b.w*b.w;
    #pragma unroll
    for (int d = 1; d < 64; d <<= 1) s += __shfl_xor(s, d);
    if (lane == 0) wnorm[code] = s;
}

// ---------------- K1: fused X-quantize + A-resident ct-pair barrier-free i8 GEMM ----------------
// R22 CHAMPION, reverted verbatim (47.4us, absmax 0.0). Each block owns a
// 64-row strip exclusively: reads it ONCE as f32 (4 threads/row), computes
// EXACT f32 xnorm in-register, quantizes to i8 into resident As
// (As[kt][row][slot], phys slot = sl ^ ((row>>1)&3)). Loop: ct-pair
// (16 MFMA 16x16x64 per 8 LDS frag-reads + 4 DMA writes), wave-private
// 3x4KB B bufs, counted vmcnt(4), ZERO barriers, 16-rows-per-instr
// 0-conflict fragment geometry (the ONLY form ever measured conflict-free;
// 32-row forms conflicted 3/3 times: R5, R6, R23), XCD row-chunk
// (bid = xcd + 8*rl). LDS = 80KB -> 2 blocks/CU.
__global__ void __launch_bounds__(256, 2)
gemm_argmin(const float* __restrict__ X, const char* __restrict__ Wq,
            const float* __restrict__ wnorm, float* __restrict__ partial) {
    __shared__ __align__(16) char As[8 * 4096];        // 32 KB: [kt][row][slot]
    __shared__ __align__(16) char Bs[4 * 3 * 4096];    // 48 KB: [wave][buf][4KB]

    const int tid  = threadIdx.x;
    const int lane = tid & 63;
    const int wave = tid >> 6;
    const int lr = lane & 15, kg = lane >> 4;

    // XCD row-chunk swizzle: bid = xcd + 8*rl; grid 512.
    const int bid = blockIdx.x;
    const int rowBase = ((bid & 7) * 64 + (bid >> 3)) * 64;
    const int colW = wave * 256;                  // wave's private col swath

    // B staging (verified 0-conflict): slot pre-swizzled by (row>>1)&3.
    const int ssw = ((lane & 3) ^ ((lane >> 3) & 3)) * 16;
    const char* bS = Wq + (size_t)(colW + (lane >> 2)) * DIM + ssw;
    char* bD = Bs + wave * 12288 + lane * 16;

#define STAGE_B(s) do {                                                       \
    const int ctp_ = (s) >> 3, kt_ = (s) & 7, buf_ = (s) % 3;                 \
    _Pragma("unroll")                                                         \
    for (int j = 0; j < 4; ++j)                                               \
        gl_lds16(bS + (size_t)(ctp_ * 64 + j * 16) * DIM + kt_ * 64,          \
                 bD + buf_ * 4096 + j * 1024);                                \
  } while (0)

    // ---- issue B(0), B(1) first: they land under the long f32 prologue ----
    STAGE_B(0);
    STAGE_B(1);

    // ---- prologue: f32 X strip -> exact xnorm + i8 into resident As ----
    // thread t: row r = t>>2, quarter q4 = t&3 (128 elements = kt pair).
    const int r = tid >> 2, q4 = tid & 3;
    const int rsw = (r >> 1) & 3;                 // row's slot XOR
    float nrm = 0.f;
    {
        const float* xP = X + (size_t)(rowBase + r) * DIM + q4 * 128;
        #pragma unroll
        for (int c = 0; c < 8; ++c) {             // 8 chunks of 16 elements
            float4 f0 = *(const float4*)(xP + c * 16);
            float4 f1 = *(const float4*)(xP + c * 16 + 4);
            float4 f2 = *(const float4*)(xP + c * 16 + 8);
            float4 f3 = *(const float4*)(xP + c * 16 + 12);
            nrm += f0.x*f0.x + f0.y*f0.y + f0.z*f0.z + f0.w*f0.w
                 + f1.x*f1.x + f1.y*f1.y + f1.z*f1.z + f1.w*f1.w
                 + f2.x*f2.x + f2.y*f2.y + f2.z*f2.z + f2.w*f2.w
                 + f3.x*f3.x + f3.y*f3.y + f3.z*f3.z + f3.w*f3.w;
            i32x4 v = { (int)pack4(f0.x, f0.y, f0.z, f0.w),
                        (int)pack4(f1.x, f1.y, f1.z, f1.w),
                        (int)pack4(f2.x, f2.y, f2.z, f2.w),
                        (int)pack4(f3.x, f3.y, f3.z, f3.w) };
            const int kt = 2 * q4 + (c >> 2), sl = c & 3;
            *(i32x4*)&As[kt * 4096 + r * 64 + (sl ^ rsw) * 16] = v;
        }
        nrm += __shfl_xor(nrm, 1);
        nrm += __shfl_xor(nrm, 2);                // lanes of a row-quartet
    }
    __syncthreads();   // As visible to all; drains B(0),B(1) too

    i32x4 acc[4][4];
    #pragma unroll
    for (int m = 0; m < 4; ++m)
        #pragma unroll
        for (int n = 0; n < 4; ++n) acc[m][n] = (i32x4)0;
    uint32_t runKey[4][4];
    #pragma unroll
    for (int m = 0; m < 4; ++m)
        #pragma unroll
        for (int rr = 0; rr < 4; ++rr) runKey[m][rr] = 0xFFFFFFFFu;

    const int fq = (kg ^ ((lr >> 1) & 3)) * 16;   // swizzled read slot (bytes)
    const char* bR = Bs + wave * 12288;

    for (int ctp = 0; ctp < 4; ++ctp) {
        #pragma unroll
        for (int kt = 0; kt < 8; ++kt) {
            const int s = ctp * 8 + kt;
            const int buf = s % 3;
            i32x4 aF[4], bF[4];
            #pragma unroll
            for (int m = 0; m < 4; ++m)
                aF[m] = *(const i32x4*)&As[kt * 4096 + (m * 16 + lr) * 64 + fq];
            #pragma unroll
            for (int n = 0; n < 4; ++n)
                bF[n] = *(const i32x4*)&bR[buf * 4096 + (n * 16 + lr) * 64 + fq];
            if (s + 2 < 32) STAGE_B(s + 2);       // depth-2, wave-private
            #pragma unroll
            for (int m = 0; m < 4; ++m)
                #pragma unroll
                for (int n = 0; n < 4; ++n)
                    acc[m][n] = __builtin_amdgcn_mfma_i32_16x16x64_i8(
                        aF[m], bF[n], acc[m][n], 0, 0, 0);
            if (s + 2 < 32)   asm volatile("s_waitcnt vmcnt(4)" ::: "memory");
            else if (s == 30) asm volatile("s_waitcnt vmcnt(0)" ::: "memory");
        }
        // ct-pair complete: fold scores into running packed keys
        #pragma unroll
        for (int n = 0; n < 4; ++n) {
            const int wcol = colW + ctp * 64 + n * 16 + lr;
            const float wn = wnorm[wcol];
            #pragma unroll
            for (int m = 0; m < 4; ++m)
                #pragma unroll
                for (int rr = 0; rr < 4; ++rr) {
                    float sc = wn - (float)acc[m][n][rr] * 0.001953125f;
                    uint32_t u = __float_as_uint(sc);
                    u = (u & 0x80000000u) ? ~u : (u | 0x80000000u);
                    runKey[m][rr] = min(runKey[m][rr],
                                        (u & ~1023u) | (uint32_t)wcol);
                }
        }
        #pragma unroll
        for (int m = 0; m < 4; ++m)
            #pragma unroll
            for (int n = 0; n < 4; ++n) acc[m][n] = (i32x4)0;
    }
#undef STAGE_B

    // ---- per-wave 16-lane col reduce -> kbuf; park xnorm in dead Bs ----
    uint32_t* kbuf = (uint32_t*)(Bs + wave * 12288);   // own region, loop done
    #pragma unroll
    for (int m = 0; m < 4; ++m)
        #pragma unroll
        for (int rr = 0; rr < 4; ++rr) {
            uint32_t k = runKey[m][rr];
            #pragma unroll
            for (int d = 1; d < 16; d <<= 1)
                k = min(k, (uint32_t)__shfl_xor((int)k, d));
            if (lr == 0) kbuf[m * 16 + kg * 4 + rr] = k;
        }
    float* xnS = (float*)(Bs + 48896);   // dead space, clear of all kbufs
    if ((tid & 3) == 0) xnS[r] = nrm;
    __syncthreads();

    // ---- wave 0: merge 4 waves' keys per row, add exact xnorm, block sum ----
    if (wave == 0) {
        const uint32_t* k0 = (const uint32_t*)(Bs);
        uint32_t k = min(min(k0[lane], k0[3072 + lane]),
                         min(k0[6144 + lane], k0[9216 + lane]));
        uint32_t sb = k & ~1023u;
        float sc = (sb & 0x80000000u) ? __uint_as_float(sb ^ 0x80000000u)
                                      : __uint_as_float(~sb);
        float v = xnS[lane] + sc;
        #pragma unroll
        for (int d = 1; d < 64; d <<= 1) v += __shfl_xor(v, d);
        if (lane == 0) partial[bid] = v;
    }
}

// ---------------- K2: final mean over 512 partials (double accum) ----------------
__global__ void __launch_bounds__(256)
finalize(const float* __restrict__ partial, float* __restrict__ out) {
    __shared__ double sm[256];
    sm[threadIdx.x] = (double)partial[threadIdx.x]
                    + (double)partial[threadIdx.x + 256];
    __syncthreads();
    for (int st = 128; st > 0; st >>= 1) {
        if (threadIdx.x < st) sm[threadIdx.x] += sm[threadIdx.x + st];
        __syncthreads();
    }
    if (threadIdx.x == 0)
        out[0] = (float)(sm[0] / (double)((size_t)N_ROWS * DIM));
}

extern "C" void kernel_launch(void* const* d_in, const int* in_sizes, int n_in,
                              void* d_out, int out_size, void* d_ws, size_t ws_size,
                              hipStream_t stream) {
    const float* X = (const float*)d_in[0];   // [32768][512]
    const float* W = (const float*)d_in[1];   // [1024][512]
    char* ws = (char*)d_ws;
    char*   Wq      = ws;                            // 512 KB @ 0
    float*  wnorm   = (float*)(ws + 524288);         // 4 KB
    float*  partial = (float*)(ws + 528384);         // 2 KB
    float*  out     = (float*)d_out;

    convertW<<<N_CODES / 4, 256, 0, stream>>>(W, Wq, wnorm);
    gemm_argmin<<<512, 256, 0, stream>>>(X, Wq, wnorm, partial);
    finalize<<<1, 256, 0, stream>>>(partial, out);
}